// Round 1
// 112.320 us; speedup vs baseline: 1.0056x; 1.0056x over previous
//
#include <hip/hip_runtime.h>
#include <cstdint>

#define B_SZ 8192
#define D_SZ 512
#define K_SZ 2048
#define EPSV 1e-8f
// 1/TEMP
#define INV_T 2.0f

typedef float floatx16 __attribute__((ext_vector_type(16)));
typedef int intx8 __attribute__((ext_vector_type(8)));

// async global->LDS, 16B per lane. LDS dest must be wave-uniform base + lane*16.
__device__ __forceinline__ void async_cp16(const void* g, void* l) {
    typedef __attribute__((address_space(1))) unsigned int gds_t;
    typedef __attribute__((address_space(3))) unsigned int lds_t;
    __builtin_amdgcn_global_load_lds((gds_t*)(unsigned long long)g, (lds_t*)l, 16, 0, 0);
}

// pack 8 fp32 -> 8 fp8 e4m3 (OCP, RNE, saturating) as int2
__device__ __forceinline__ int2 pack_fp8x8(float4 a0, float4 a1) {
    int w0 = __builtin_amdgcn_cvt_pk_fp8_f32(a0.x, a0.y, 0, false);
    w0 = __builtin_amdgcn_cvt_pk_fp8_f32(a0.z, a0.w, w0, true);
    int w1 = __builtin_amdgcn_cvt_pk_fp8_f32(a1.x, a1.y, 0, false);
    w1 = __builtin_amdgcn_cvt_pk_fp8_f32(a1.z, a1.w, w1, true);
    return make_int2(w0, w1);
}

// ---------------------------------------------------------------------------
// Kernel 1 (merged prep+gather) — unchanged from R11 (verified).
// ---------------------------------------------------------------------------
__global__ __launch_bounds__(256) void k_prep(
    const float* __restrict__ zi, const float* __restrict__ zj,
    const int* __restrict__ perm,
    float* __restrict__ ri_arr, float* __restrict__ pos_arr,
    unsigned char* __restrict__ A,
    float4* __restrict__ kmeta, unsigned char* __restrict__ G,
    float* __restrict__ rowacc, float* __restrict__ out)
{
    int w = threadIdx.x >> 6, l = threadIdx.x & 63;
    if (blockIdx.x < 2048) {
        if (blockIdx.x < 64)
            rowacc[blockIdx.x * 256 + threadIdx.x] = 0.f;   // pe[8192] ++ pc[8192]
        if (blockIdx.x == 0 && threadIdx.x < 3) out[threadIdx.x] = 0.f;
        int row = blockIdx.x * 4 + w;
        const float4* zi4 = (const float4*)(zi + (size_t)row * D_SZ);
        const float4* zj4 = (const float4*)(zj + (size_t)row * D_SZ);
        float4 a0 = zi4[2 * l], a1 = zi4[2 * l + 1];
        float4 b0 = zj4[2 * l], b1 = zj4[2 * l + 1];
        float si = a0.x * a0.x + a0.y * a0.y + a0.z * a0.z + a0.w * a0.w
                 + a1.x * a1.x + a1.y * a1.y + a1.z * a1.z + a1.w * a1.w;
        float sj = b0.x * b0.x + b0.y * b0.y + b0.z * b0.z + b0.w * b0.w
                 + b1.x * b1.x + b1.y * b1.y + b1.z * b1.z + b1.w * b1.w;
        float dd = a0.x * b0.x + a0.y * b0.y + a0.z * b0.z + a0.w * b0.w
                 + a1.x * b1.x + a1.y * b1.y + a1.z * b1.z + a1.w * b1.w;
        for (int m = 1; m < 64; m <<= 1) {
            si += __shfl_xor(si, m);
            sj += __shfl_xor(sj, m);
            dd += __shfl_xor(dd, m);
        }
        if (l == 0) {
            float ni = sqrtf(si), nj = sqrtf(sj);
            ri_arr[row] = INV_T / fmaxf(ni, 1e-6f);   // norms ~22; eps never binds
            pos_arr[row] = dd / fmaxf(ni * nj, EPSV) * INV_T;
        }
        *(int2*)(A + (size_t)row * D_SZ + l * 8) = pack_fp8x8(a0, a1);
    } else {
        __shared__ float srj[4];
        int g = (blockIdx.x - 2048) * 4 + w;        // 0..4095
        int c0 = perm[g >> 1];
        int c = c0 + (g & 1);                       // actual z_j row
        const float4* src = (const float4*)(zj + (size_t)c * D_SZ);
        float4 a0 = src[2 * l], a1 = src[2 * l + 1];
        float s = a0.x * a0.x + a0.y * a0.y + a0.z * a0.z + a0.w * a0.w
                + a1.x * a1.x + a1.y * a1.y + a1.z * a1.z + a1.w * a1.w;
        for (int m = 1; m < 64; m <<= 1) s += __shfl_xor(s, m);
        if (l == 0) srj[w] = 1.0f / fmaxf(sqrtf(s), 1e-6f);
        __syncthreads();
        if ((w & 1) == 0 && l == 0)
            kmeta[g >> 1] = make_float4(srj[w], srj[w + 1],
                                        __int_as_float(c0), 0.f);
        *(int2*)(G + (size_t)g * D_SZ + l * 8) = pack_fp8x8(a0, a1);
    }
}

// ---------------------------------------------------------------------------
// Kernel 2 (R12): MX-fp8 MFMA GEMM, S^T = G . A^T, 256x256 tile, 8 waves,
// wave = 128(g) x 64(anchor) = 4x2 fragments of 32x32 (acc 128 VGPR).
// T3+T4+T5 port: 3-deep LDS ring (3 x (16+16) KB = 96 KB), counted
// s_waitcnt vmcnt(4) (one 4-load stage group always in flight, never drained
// to 0 mid-loop), exactly ONE raw s_barrier per K-step (no compiler
// vmcnt(0)+lgkmcnt(0) drain -- that drain was the 2-phase structure's stall),
// manual lgkmcnt(0)+sched_barrier(0) before the MFMA cluster (rule #18),
// s_setprio(1) around the 8-MFMA cluster (T5).
// Ring timeline (hand-verified): buf kb%3 holds K-block kb. STAGE(kb+2) is
// issued only after the top-of-iter barrier, at which point every wave has
// retired its reads of that buffer (reads -> lgkmcnt(0) -> mfma -> barrier).
// vmcnt(4)+barrier guarantees all waves' DMA for buf[cur] has landed.
// Swizzle: same measured-0-conflict 16B-chunk scheme (rows still 64 B).
// Epilogue: same verified pair-select + atomicAdd rowacc, now 4 tm subtiles.
// XCD map: xcd = bid&7 owns 2 g-panels (512 G rows = 256 KB, L2-resident).
// ---------------------------------------------------------------------------
__global__ __launch_bounds__(512, 2) void k_gemm(
    const unsigned char* __restrict__ A,    // [8192][512] fp8  (anchors)
    const unsigned char* __restrict__ G,    // [4096][512] fp8  (gathered)
    const float4* __restrict__ kmeta,       // [2048]  {rj0, rj1, c0f, -}
    const float* __restrict__ ri_arr,       // [8192]  INV_T/ni
    const float* __restrict__ pos_arr,      // [8192]
    float* __restrict__ rowacc)             // [2][8192] atomic accumulators
{
    __shared__ unsigned char Asl[3][256 * 64];   // anchor tiles, 16 KB each
    __shared__ unsigned char Gsl[3][256 * 64];   // g tiles
    const int tid = threadIdx.x;
    const int l = tid & 63, w = tid >> 6;
    const int wm = w >> 2, wn = w & 3;      // wm: g-half (0..1), wn: anchor quarter (0..3)
    const int ln = l & 31, q = l >> 5;      // 32x32 MFMA lane decomposition

    // XCD-aware tile mapping: 512 blocks; xcd = bid&7 owns g-panels xcd*2..+2
    const int bid = blockIdx.x;
    const int xcd = bid & 7;
    const int slot = bid >> 3;              // 0..63
    const int gTile = xcd * 2 + (slot & 1); // 0..15 (G row panel, 256 rows)
    const int aTile = slot >> 1;            // 0..31 (anchor panel, 256 rows)
    const int gBase = gTile * 256;
    const int aBase = aTile * 256;

    // staging offsets (bytes); 1024 16B-chunks per array per K-block
    // (2 iters x 512 threads). Same XOR swizzle as R10/R11 (0 conflicts).
    size_t aOff[2], gOff[2];
    int ldsOff[2];
    #pragma unroll
    for (int it = 0; it < 2; ++it) {
        int fc = it * 512 + tid;            // 16B chunk 0..1023
        int r = fc >> 2, s = fc & 3;
        int scc = s ^ ((r ^ (r >> 2)) & 3); // XOR swizzle source 16B chunk
        aOff[it] = (size_t)(aBase + r) * D_SZ + scc * 16;
        gOff[it] = (size_t)(gBase + r) * D_SZ + scc * 16;
        ldsOff[it] = fc * 16;
    }

    floatx16 acc[4][2] = {};                // [tm: g-subtile][tn: anchor-subtile]

    // frag read addresses (bytes in a 16 KB buffer): lane needs k-bytes
    // [q*32, q*32+32) of its row = pre-swizzle chunks {2q, 2q+1}
    int aAddr[2][2], gAddr[4][2];
    #pragma unroll
    for (int tn = 0; tn < 2; ++tn) {
        int ar = wn * 64 + tn * 32 + ln;    // anchor row in tile (N-operand)
        int xa = (ar ^ (ar >> 2)) & 3;
        aAddr[tn][0] = ar * 64 + ((2 * q) ^ xa) * 16;
        aAddr[tn][1] = ar * 64 + ((2 * q + 1) ^ xa) * 16;
    }
    #pragma unroll
    for (int tm = 0; tm < 4; ++tm) {
        int gr = wm * 128 + tm * 32 + ln;   // g row in tile (M-operand)
        int xg = (gr ^ (gr >> 2)) & 3;
        gAddr[tm][0] = gr * 64 + ((2 * q) ^ xg) * 16;
        gAddr[tm][1] = gr * 64 + ((2 * q + 1) ^ xg) * 16;
    }

    // stage K-block kb into ring buffer `buf` (4 async_cp16 per thread)
    auto STAGE = [&](int buf, int kb) {
        #pragma unroll
        for (int it = 0; it < 2; ++it) {
            async_cp16(A + aOff[it] + (size_t)kb * 64, &Asl[buf][ldsOff[it]]);
            async_cp16(G + gOff[it] + (size_t)kb * 64, &Gsl[buf][ldsOff[it]]);
        }
    };

    // prologue: fill first two ring slots
    STAGE(0, 0);
    STAGE(1, 1);

    #pragma unroll
    for (int kb = 0; kb < 8; ++kb) {
        const int cur = kb % 3;
        // wait for buf[cur]'s 4 stage loads (the newest 4 = next K-block stay
        // in flight -- NEVER drain vmcnt to 0 mid-loop). vmcnt is in-order.
        if (kb < 7) {
            asm volatile("s_waitcnt vmcnt(4)" ::: "memory");
        } else {
            asm volatile("s_waitcnt vmcnt(0)" ::: "memory");
        }
        __builtin_amdgcn_s_barrier();       // ALL waves' DMA for cur landed;
                                            // all waves done reading buf[(kb+2)%3]'s old data
        if (kb < 6) STAGE((kb + 2) % 3, kb + 2);   // overwrite oldest slot

        intx8 af[2], gf[4];
        #pragma unroll
        for (int tn = 0; tn < 2; ++tn) {
            int4 lo = *(const int4*)&Asl[cur][aAddr[tn][0]];
            int4 hi = *(const int4*)&Asl[cur][aAddr[tn][1]];
            af[tn][0] = lo.x; af[tn][1] = lo.y; af[tn][2] = lo.z; af[tn][3] = lo.w;
            af[tn][4] = hi.x; af[tn][5] = hi.y; af[tn][6] = hi.z; af[tn][7] = hi.w;
        }
        #pragma unroll
        for (int tm = 0; tm < 4; ++tm) {
            int4 lo = *(const int4*)&Gsl[cur][gAddr[tm][0]];
            int4 hi = *(const int4*)&Gsl[cur][gAddr[tm][1]];
            gf[tm][0] = lo.x; gf[tm][1] = lo.y; gf[tm][2] = lo.z; gf[tm][3] = lo.w;
            gf[tm][4] = hi.x; gf[tm][5] = hi.y; gf[tm][6] = hi.z; gf[tm][7] = hi.w;
        }
        // reads must retire before next iter's barrier (so STAGE can overwrite)
        asm volatile("s_waitcnt lgkmcnt(0)" ::: "memory");
        __builtin_amdgcn_sched_barrier(0);  // rule #18: pin MFMA after the wait

        __builtin_amdgcn_s_setprio(1);      // T5: favor the MFMA cluster
        #pragma unroll
        for (int tm = 0; tm < 4; ++tm)
            #pragma unroll
            for (int tn = 0; tn < 2; ++tn)
                acc[tm][tn] = __builtin_amdgcn_mfma_scale_f32_32x32x64_f8f6f4(
                    gf[tm], af[tn], acc[tm][tn],
                    0, 0,                       // cbsz/blgp = fp8 e4m3
                    0, 0x7f7f7f7f,              // scale A: all-ones (2^0)
                    0, 0x7f7f7f7f);             // scale B: all-ones (2^0)
        __builtin_amdgcn_s_setprio(0);
    }

    // ---- fused epilogue: pair-select then exp, in-register reduction ----
    // C/D layout (32x32): col = anchor = ln (+tn*32), row = g = (reg&3) +
    // 8*(reg>>2) + 4*q (+tm*32 +wm*128). Regs 4j..4j+3 hold 4 consecutive g,
    // i.e. column pairs k0 = gTile*128 + wm*64 + tm*16 + 4j + 2q and k0+1.
    int anc[2]; float riv[2], pv[2], pe[2] = {0.f, 0.f}, pc[2] = {0.f, 0.f};
    #pragma unroll
    for (int tn = 0; tn < 2; ++tn) {
        anc[tn] = aBase + wn * 64 + tn * 32 + ln;
        riv[tn] = ri_arr[anc[tn]];          // INV_T / ni
        pv[tn] = pos_arr[anc[tn]];
    }
    #pragma unroll
    for (int tm = 0; tm < 4; ++tm) {
        #pragma unroll
        for (int j = 0; j < 4; ++j) {
            int k0 = gTile * 128 + wm * 64 + tm * 16 + 4 * j + 2 * q;
            float4 m0 = kmeta[k0];
            float4 m1 = kmeta[k0 + 1];
            #pragma unroll
            for (int p = 0; p < 2; ++p) {
                float4 md = p ? m1 : m0;
                int c0 = __float_as_int(md.z);
                int re = 4 * j + 2 * p;     // even-g reg; odd is re+1
                #pragma unroll
                for (int tn = 0; tn < 2; ++tn) {
                    bool sel = (c0 >= anc[tn]);             // use column c0+1
                    float v = sel ? acc[tm][tn][re + 1] : acc[tm][tn][re];
                    float rj = sel ? md.y : md.x;
                    float logit = v * riv[tn] * rj;
                    pe[tn] += __expf(logit);
                    pc[tn] += (logit > pv[tn]) ? 1.f : 0.f;
                }
            }
        }
    }
    #pragma unroll
    for (int tn = 0; tn < 2; ++tn) {
        pe[tn] += __shfl_xor(pe[tn], 32);
        pc[tn] += __shfl_xor(pc[tn], 32);
        if (q == 0) {
            atomicAdd(&rowacc[anc[tn]], pe[tn]);
            atomicAdd(&rowacc[B_SZ + anc[tn]], pc[tn]);
        }
    }
}

// ---------------------------------------------------------------------------
// Kernel 3: tiny finalize — unchanged.
// ---------------------------------------------------------------------------
__global__ __launch_bounds__(256) void k_final(
    const float* __restrict__ rowacc, const float* __restrict__ pos_arr,
    float* __restrict__ out)
{
    int row = blockIdx.x * 256 + threadIdx.x;
    float pe = rowacc[row];
    float pc = rowacc[B_SZ + row];
    float pos = pos_arr[row];
    float loss = logf(__expf(pos) + pe) - pos;   // logsumexp - pos (logits bounded)
    float a1 = (pc < 0.5f) ? 1.f : 0.f;          // no neg strictly > pos
    float a5 = (pc < 4.5f) ? 1.f : 0.f;          // at most 4 negs strictly > pos
    for (int m = 1; m < 64; m <<= 1) {
        loss += __shfl_xor(loss, m);
        a1 += __shfl_xor(a1, m);
        a5 += __shfl_xor(a5, m);
    }
    __shared__ float red[3][4];
    int w = threadIdx.x >> 6, l = threadIdx.x & 63;
    if (l == 0) { red[0][w] = loss; red[1][w] = a1; red[2][w] = a5; }
    __syncthreads();
    if (threadIdx.x == 0) {
        float L = red[0][0] + red[0][1] + red[0][2] + red[0][3];
        float A1 = red[1][0] + red[1][1] + red[1][2] + red[1][3];
        float A5 = red[2][0] + red[2][1] + red[2][2] + red[2][3];
        atomicAdd(&out[0], L / (float)B_SZ);
        atomicAdd(&out[1], A1 * (100.f / (float)B_SZ));
        atomicAdd(&out[2], A5 * (100.f / (float)B_SZ));
    }
}

// ---------------------------------------------------------------------------
extern "C" void kernel_launch(void* const* d_in, const int* in_sizes, int n_in,
                              void* d_out, int out_size, void* d_ws, size_t ws_size,
                              hipStream_t stream)
{
    const float* zi = (const float*)d_in[0];
    const float* zj = (const float*)d_in[1];
    const int* perm = (const int*)d_in[2];
    float* out = (float*)d_out;

    // workspace layout (all 16B aligned)
    char* p = (char*)d_ws;
    unsigned char* A = (unsigned char*)p;    p += (size_t)B_SZ * D_SZ;          // 4 MB
    unsigned char* G = (unsigned char*)p;    p += (size_t)2 * K_SZ * D_SZ;      // 2 MB
    float* ri_arr = (float*)p;               p += (size_t)B_SZ * 4;
    float* pos_arr = (float*)p;              p += (size_t)B_SZ * 4;
    float4* kmeta = (float4*)p;              p += (size_t)K_SZ * 16;            // 32 KB
    float* rowacc = (float*)p;               p += (size_t)2 * B_SZ * 4;         // 64 KB

    k_prep<<<2048 + 1024, 256, 0, stream>>>(zi, zj, perm, ri_arr, pos_arr, A,
                                            kmeta, G, rowacc, out);
    k_gemm<<<512, 512, 0, stream>>>(A, G, kmeta, ri_arr, pos_arr, rowacc);
    k_final<<<32, 256, 0, stream>>>(rowacc, pos_arr, out);
}